// Round 1
// baseline (463.155 us; speedup 1.0000x reference)
//
#include <hip/hip_runtime.h>
#include <stdint.h>

typedef __attribute__((ext_vector_type(8))) short    bf16x8;
typedef __attribute__((ext_vector_type(4))) float    f32x4;
typedef __attribute__((ext_vector_type(8))) uint16_t u16x8;

static constexpr int Bb = 4, Ss = 2048, Dd = 1024, Hh = 16, DKk = 64;
static constexpr float LOG2E = 1.44269504088896340736f;

__device__ __forceinline__ uint16_t f2bf(float f) {
  uint32_t u = __builtin_bit_cast(uint32_t, f);
  u += 0x7FFFu + ((u >> 16) & 1u);
  return (uint16_t)(u >> 16);
}
__device__ __forceinline__ float bf2f(uint16_t b) {
  return __builtin_bit_cast(float, (uint32_t)b << 16);
}
__device__ __forceinline__ f32x4 mfma16(bf16x8 a, bf16x8 b, f32x4 c) {
  return __builtin_amdgcn_mfma_f32_16x16x32_bf16(a, b, c, 0, 0, 0);
}

// ---------------- weight cast: fp32 -> bf16 ----------------
__global__ __launch_bounds__(256) void cast_w(const float* __restrict__ wq,
                                              const float* __restrict__ wk,
                                              const float* __restrict__ wv,
                                              const float* __restrict__ wo,
                                              uint16_t* __restrict__ wb) {
  const int z = blockIdx.y;
  const float* src = (z == 0) ? wq : (z == 1) ? wk : (z == 2) ? wv : wo;
  uint16_t* dst = wb + (size_t)z * (Dd * Dd);
  const int t = blockIdx.x * 256 + threadIdx.x;  // 0..131071
  const int i = t * 8;
  f32x4 a = *(const f32x4*)(src + i);
  f32x4 b = *(const f32x4*)(src + i + 4);
  u16x8 o;
  o[0] = f2bf(a[0]); o[1] = f2bf(a[1]); o[2] = f2bf(a[2]); o[3] = f2bf(a[3]);
  o[4] = f2bf(b[0]); o[5] = f2bf(b[1]); o[6] = f2bf(b[2]); o[7] = f2bf(b[3]);
  *(u16x8*)(dst + i) = o;
}

// ---------------- GEMM: C = A @ W^T + bias ----------------
// A: [8192, 1024]  (fp32 for MODE 0..2, bf16 for MODE 3)
// W: [1024, 1024] bf16 row-major [out, in]
// MODE 0: out16 = q_ws  [B,H,S,DK] bf16, value = (acc+bias)*0.125
// MODE 1: out16 = k_ws  [B,H,S,DK] bf16
// MODE 2: out16 = vt_ws [B,H,DK,S] bf16 (transposed store)
// MODE 3: out32 = d_out [8192,1024] fp32
template <int MODE>
__global__ __launch_bounds__(256) void gemm_k(const float* __restrict__ A32,
                                              const uint16_t* __restrict__ A16,
                                              const uint16_t* __restrict__ W,
                                              const float* __restrict__ bias,
                                              uint16_t* __restrict__ out16,
                                              float* __restrict__ out32) {
  constexpr int K = 1024;
  __shared__ __align__(16) uint16_t As[128 * 64];
  __shared__ __align__(16) uint16_t Bs[128 * 64];

  const int tid = threadIdx.x;
  const int lane = tid & 63, wid = tid >> 6;
  const int wr = wid >> 1, wc = wid & 1;
  const int cl = lane & 15, hi = lane >> 4;
  const int m0 = blockIdx.x * 128, n0 = blockIdx.y * 128;

  // staging: 1024 16B-chunks per 128x64 tile; 4 per thread
  int adst[4], asrc[4], bsrc[4];
#pragma unroll
  for (int c = 0; c < 4; ++c) {
    int i = c * 256 + tid;
    int row = i >> 3, cc = i & 7;
    adst[c] = row * 64 + ((cc ^ (row & 7)) * 8);
    asrc[c] = (m0 + row) * K + cc * 8;
    bsrc[c] = (n0 + row) * K + cc * 8;
  }
  // fragment read offsets
  int aoff[4][2], boff[4][2];
#pragma unroll
  for (int m = 0; m < 4; ++m)
#pragma unroll
    for (int kk = 0; kk < 2; ++kk) {
      int rowa = wr * 64 + m * 16 + cl;
      int rowb = wc * 64 + m * 16 + cl;
      int ch = kk * 4 + hi;
      aoff[m][kk] = rowa * 64 + ((ch ^ (rowa & 7)) * 8);
      boff[m][kk] = rowb * 64 + ((ch ^ (rowb & 7)) * 8);
    }

  f32x4 acc[4][4];
#pragma unroll
  for (int m = 0; m < 4; ++m)
#pragma unroll
    for (int n = 0; n < 4; ++n) acc[m][n] = (f32x4){0.f, 0.f, 0.f, 0.f};

  for (int kt = 0; kt < K / 64; ++kt) {
    const int k0 = kt * 64;
#pragma unroll
    for (int c = 0; c < 4; ++c) {
      bf16x8 v;
      if constexpr (MODE < 3) {
        const float* p = A32 + asrc[c] + k0;
        f32x4 x = *(const f32x4*)p;
        f32x4 y = *(const f32x4*)(p + 4);
        v[0] = (short)f2bf(x[0]); v[1] = (short)f2bf(x[1]);
        v[2] = (short)f2bf(x[2]); v[3] = (short)f2bf(x[3]);
        v[4] = (short)f2bf(y[0]); v[5] = (short)f2bf(y[1]);
        v[6] = (short)f2bf(y[2]); v[7] = (short)f2bf(y[3]);
      } else {
        v = *(const bf16x8*)(A16 + asrc[c] + k0);
      }
      *(bf16x8*)(As + adst[c]) = v;
      *(bf16x8*)(Bs + adst[c]) = *(const bf16x8*)(W + bsrc[c] + k0);
    }
    __syncthreads();
#pragma unroll
    for (int kk = 0; kk < 2; ++kk) {
      bf16x8 af[4], bf[4];
#pragma unroll
      for (int m = 0; m < 4; ++m) af[m] = *(const bf16x8*)(As + aoff[m][kk]);
#pragma unroll
      for (int n = 0; n < 4; ++n) bf[n] = *(const bf16x8*)(Bs + boff[n][kk]);
#pragma unroll
      for (int m = 0; m < 4; ++m)
#pragma unroll
        for (int n = 0; n < 4; ++n) acc[m][n] = mfma16(af[m], bf[n], acc[m][n]);
    }
    __syncthreads();
  }

  // epilogue
#pragma unroll
  for (int n = 0; n < 4; ++n) {
    const int col = n0 + wc * 64 + n * 16 + cl;
    const float bv = bias[col];
    const int h = col >> 6, dk = col & 63;
#pragma unroll
    for (int m = 0; m < 4; ++m) {
      const int row0 = m0 + wr * 64 + m * 16 + hi * 4;
#pragma unroll
      for (int j = 0; j < 4; ++j) {
        const int row = row0 + j;
        float val = acc[m][n][j] + bv;
        const int b = row >> 11, s = row & 2047;
        if constexpr (MODE == 0) {
          out16[((size_t)(b * Hh + h) * Ss + s) * 64 + dk] = f2bf(val * 0.125f);
        } else if constexpr (MODE == 1) {
          out16[((size_t)(b * Hh + h) * Ss + s) * 64 + dk] = f2bf(val);
        } else if constexpr (MODE == 2) {
          out16[((size_t)(b * Hh + h) * 64 + dk) * Ss + s] = f2bf(val);
        } else {
          out32[(size_t)row * Dd + col] = val;
        }
      }
    }
  }
}

// ---------------- flash attention ----------------
// q_ws/k_ws: [B*H, S, 64] bf16 (q pre-scaled by 0.125); vt_ws: [B*H, 64, S] bf16
// o_ws: [B, S, D] bf16 (heads recombined)
__global__ __launch_bounds__(512) void attn_k(const uint16_t* __restrict__ q_ws,
                                              const uint16_t* __restrict__ k_ws,
                                              const uint16_t* __restrict__ vt_ws,
                                              uint16_t* __restrict__ o_ws) {
  __shared__ __align__(16) uint16_t Ks[64 * 64];
  __shared__ __align__(16) uint16_t Vs[64 * 64];
  __shared__ __align__(16) uint16_t Ps[8][16 * 64];

  const int tid = threadIdx.x;
  const int lane = tid & 63, wid = tid >> 6;
  const int cl = lane & 15, hi = lane >> 4;
  const int bh = blockIdx.y;
  const int b = bh >> 4, h = bh & 15;
  const int q0 = blockIdx.x * 128;

  // hoist Q fragments (rows q0 + wid*16 + cl)
  bf16x8 qf[2];
  {
    const uint16_t* qrow = q_ws + ((size_t)bh * Ss + q0 + wid * 16 + cl) * 64;
#pragma unroll
    for (int kk = 0; kk < 2; ++kk) qf[kk] = *(const bf16x8*)(qrow + kk * 32 + hi * 8);
  }

  float m[4] = {-1e30f, -1e30f, -1e30f, -1e30f};
  float lsum[4] = {0.f, 0.f, 0.f, 0.f};
  f32x4 o_acc[4];
#pragma unroll
  for (int f = 0; f < 4; ++f) o_acc[f] = (f32x4){0.f, 0.f, 0.f, 0.f};

  // staging (one 16B chunk per thread; 512 threads cover a 64x64 bf16 tile)
  const int srow = tid >> 3, scc = tid & 7;
  const int sdst = srow * 64 + ((scc ^ (srow & 7)) * 8);
  const uint16_t* ksrc = k_ws + (size_t)bh * Ss * 64 + srow * 64 + scc * 8;
  const uint16_t* vsrc = vt_ws + ((size_t)bh * 64 + srow) * Ss + scc * 8;

  // fragment offsets (shared formula for K and Vt reads)
  int boff[4][2];
#pragma unroll
  for (int f = 0; f < 4; ++f)
#pragma unroll
    for (int kk = 0; kk < 2; ++kk) {
      int row = f * 16 + cl;
      int ch = kk * 4 + hi;
      boff[f][kk] = row * 64 + ((ch ^ (row & 7)) * 8);
    }
  int poff[2];
#pragma unroll
  for (int ks = 0; ks < 2; ++ks) poff[ks] = cl * 64 + (((ks * 4 + hi) ^ (cl & 7)) * 8);

  uint16_t* pb = Ps[wid];

  for (int kt = 0; kt < Ss / 64; ++kt) {
    const int kv0 = kt * 64;
    *(bf16x8*)(Ks + sdst) = *(const bf16x8*)(ksrc + kv0 * 64);
    *(bf16x8*)(Vs + sdst) = *(const bf16x8*)(vsrc + kv0);
    __syncthreads();

    // S = Q K^T (q pre-scaled)
    f32x4 sa[4];
#pragma unroll
    for (int f = 0; f < 4; ++f) sa[f] = (f32x4){0.f, 0.f, 0.f, 0.f};
#pragma unroll
    for (int kk = 0; kk < 2; ++kk) {
#pragma unroll
      for (int f = 0; f < 4; ++f) {
        bf16x8 kf = *(const bf16x8*)(Ks + boff[f][kk]);
        sa[f] = mfma16(qf[kk], kf, sa[f]);
      }
    }

    // online softmax (rows hi*4+j, cols across cl and f)
    float al[4];
#pragma unroll
    for (int j = 0; j < 4; ++j) {
      float t = fmaxf(fmaxf(sa[0][j], sa[1][j]), fmaxf(sa[2][j], sa[3][j]));
      t = fmaxf(t, __shfl_xor(t, 1));
      t = fmaxf(t, __shfl_xor(t, 2));
      t = fmaxf(t, __shfl_xor(t, 4));
      t = fmaxf(t, __shfl_xor(t, 8));
      const float mn = fmaxf(m[j], t);
      al[j] = __builtin_amdgcn_exp2f((m[j] - mn) * LOG2E);
      m[j] = mn;
      float ps = 0.f;
#pragma unroll
      for (int f = 0; f < 4; ++f) {
        float p = __builtin_amdgcn_exp2f((sa[f][j] - mn) * LOG2E);
        sa[f][j] = p;
        ps += p;
      }
      ps += __shfl_xor(ps, 1);
      ps += __shfl_xor(ps, 2);
      ps += __shfl_xor(ps, 4);
      ps += __shfl_xor(ps, 8);
      lsum[j] = lsum[j] * al[j] + ps;
    }
#pragma unroll
    for (int f = 0; f < 4; ++f)
#pragma unroll
      for (int j = 0; j < 4; ++j) o_acc[f][j] *= al[j];

    // P -> per-wave LDS (bf16, swizzled), then PV
#pragma unroll
    for (int f = 0; f < 4; ++f)
#pragma unroll
      for (int j = 0; j < 4; ++j) {
        const int r = hi * 4 + j, c = f * 16 + cl;
        const int el = r * 64 + (((c >> 3) ^ (r & 7)) * 16) / 2 + (c & 7);
        pb[el] = f2bf(sa[f][j]);
      }
    asm volatile("s_waitcnt lgkmcnt(0)" ::: "memory");
    __builtin_amdgcn_sched_barrier(0);
#pragma unroll
    for (int ks = 0; ks < 2; ++ks) {
      bf16x8 pf = *(const bf16x8*)(pb + poff[ks]);
#pragma unroll
      for (int f = 0; f < 4; ++f) {
        bf16x8 vf = *(const bf16x8*)(Vs + boff[f][ks]);
        o_acc[f] = mfma16(pf, vf, o_acc[f]);
      }
    }
    __syncthreads();
  }

  // epilogue: normalize + recombine heads into [B,S,D]
  float inv[4];
#pragma unroll
  for (int j = 0; j < 4; ++j) inv[j] = 1.0f / lsum[j];
#pragma unroll
  for (int f = 0; f < 4; ++f)
#pragma unroll
    for (int j = 0; j < 4; ++j) {
      const int r = hi * 4 + j;
      const int srow_g = q0 + wid * 16 + r;
      const int col = h * 64 + f * 16 + cl;
      o_ws[((size_t)b * Ss + srow_g) * Dd + col] = f2bf(o_acc[f][j] * inv[j]);
    }
}

// ---------------- launch ----------------
extern "C" void kernel_launch(void* const* d_in, const int* in_sizes, int n_in,
                              void* d_out, int out_size, void* d_ws, size_t ws_size,
                              hipStream_t stream) {
  const float* Q  = (const float*)d_in[0];
  const float* K  = (const float*)d_in[1];
  const float* V  = (const float*)d_in[2];
  const float* Wq = (const float*)d_in[3];
  const float* bq = (const float*)d_in[4];
  const float* Wk = (const float*)d_in[5];
  const float* bk = (const float*)d_in[6];
  const float* Wv = (const float*)d_in[7];
  const float* bv = (const float*)d_in[8];
  const float* Wo = (const float*)d_in[9];
  const float* bo = (const float*)d_in[10];

  uint16_t* ws    = (uint16_t*)d_ws;
  uint16_t* wb    = ws;                       // 4 x 1M bf16 weights
  uint16_t* q_ws  = wb + (size_t)4 * 1048576; // [B*H, S, 64]
  uint16_t* k_ws  = q_ws + (size_t)8388608;   // [B*H, S, 64]
  uint16_t* vt_ws = k_ws + (size_t)8388608;   // [B*H, 64, S]
  uint16_t* o_ws  = vt_ws + (size_t)8388608;  // [B, S, D]
  float* out = (float*)d_out;

  cast_w<<<dim3(512, 4), 256, 0, stream>>>(Wq, Wk, Wv, Wo, wb);
  gemm_k<0><<<dim3(64, 8), 256, 0, stream>>>(Q, nullptr, wb + 0 * 1048576, bq, q_ws, nullptr);
  gemm_k<1><<<dim3(64, 8), 256, 0, stream>>>(K, nullptr, wb + 1 * 1048576, bk, k_ws, nullptr);
  gemm_k<2><<<dim3(64, 8), 256, 0, stream>>>(V, nullptr, wb + 2 * 1048576, bv, vt_ws, nullptr);
  attn_k<<<dim3(16, 64), 512, 0, stream>>>(q_ws, k_ws, vt_ws, o_ws);
  gemm_k<3><<<dim3(64, 8), 256, 0, stream>>>(nullptr, o_ws, wb + 3 * 1048576, bo, nullptr, out);
}

// Round 2
// 378.881 us; speedup vs baseline: 1.2224x; 1.2224x over previous
//
#include <hip/hip_runtime.h>
#include <stdint.h>

typedef __attribute__((ext_vector_type(8))) short    bf16x8;
typedef __attribute__((ext_vector_type(4))) float    f32x4;
typedef __attribute__((ext_vector_type(8))) uint16_t u16x8;
typedef __attribute__((ext_vector_type(2))) uint32_t u32x2;

static constexpr float QSCALE = 0.18033688011112042f;  // 0.125 * log2(e)

__device__ __forceinline__ uint16_t f2bf(float f) {
  uint32_t u = __builtin_bit_cast(uint32_t, f);
  u += 0x7FFFu + ((u >> 16) & 1u);
  return (uint16_t)(u >> 16);
}
__device__ __forceinline__ f32x4 mfma16(bf16x8 a, bf16x8 b, f32x4 c) {
  return __builtin_amdgcn_mfma_f32_16x16x32_bf16(a, b, c, 0, 0, 0);
}

typedef const __attribute__((address_space(1))) void gas1_t;
typedef __attribute__((address_space(3))) void las3_t;
__device__ __forceinline__ void gload16(const void* g, void* l) {
  __builtin_amdgcn_global_load_lds((gas1_t*)g, (las3_t*)l, 16, 0, 0);
}

__device__ __forceinline__ f32x4 max4(f32x4 a, f32x4 b) {
  f32x4 r;
  r[0] = fmaxf(a[0], b[0]); r[1] = fmaxf(a[1], b[1]);
  r[2] = fmaxf(a[2], b[2]); r[3] = fmaxf(a[3], b[3]);
  return r;
}

// ---------------- cast all fp32 inputs -> bf16 in ws ----------------
// blocks [0,12288): Q,K,V (4096 each). blocks [12288,14336): Wq,Wk,Wv,Wo (512 each).
__global__ __launch_bounds__(256) void cast_all(const float* __restrict__ Q,
                                                const float* __restrict__ K,
                                                const float* __restrict__ V,
                                                const float* __restrict__ Wq,
                                                const float* __restrict__ Wk,
                                                const float* __restrict__ Wv,
                                                const float* __restrict__ Wo,
                                                uint16_t* __restrict__ ws) {
  const int bx = blockIdx.x;
  const float* src;
  uint16_t* dst;
  int off;
  if (bx < 12288) {
    const int seg = bx >> 12, r = bx & 4095;
    src = (seg == 0) ? Q : (seg == 1) ? K : V;
    dst = ws + 4194304 + (size_t)seg * 8388608;
    off = r * 2048 + threadIdx.x * 8;
  } else {
    const int t = bx - 12288;
    const int seg = t >> 9, r = t & 511;
    src = (seg == 0) ? Wq : (seg == 1) ? Wk : (seg == 2) ? Wv : Wo;
    dst = ws + (size_t)seg * 1048576;
    off = r * 2048 + threadIdx.x * 8;
  }
  f32x4 a = *(const f32x4*)(src + off);
  f32x4 b = *(const f32x4*)(src + off + 4);
  u16x8 o;
  o[0] = f2bf(a[0]); o[1] = f2bf(a[1]); o[2] = f2bf(a[2]); o[3] = f2bf(a[3]);
  o[4] = f2bf(b[0]); o[5] = f2bf(b[1]); o[6] = f2bf(b[2]); o[7] = f2bf(b[3]);
  *(u16x8*)(dst + off) = o;
}

// ---------------- bf16 GEMM: C = A @ W^T + bias (m97 structure) ----------------
// A: [8192,1024] bf16. W: [1024,1024] bf16 [out,in].
// MODE 0: q_ws [B,H,S,64], val=(acc+b)*QSCALE (log2-domain).  MODE 1: k_ws.
// MODE 2: vt_ws [B,H,64,S] transposed.  MODE 3: d_out fp32.
template <int MODE>
__global__ __launch_bounds__(256) void gemm_k(const uint16_t* __restrict__ A,
                                              const uint16_t* __restrict__ W,
                                              const float* __restrict__ bias,
                                              uint16_t* __restrict__ out16,
                                              float* __restrict__ out32) {
  __shared__ __align__(16) uint16_t As[128 * 64];
  __shared__ __align__(16) uint16_t Bs[128 * 64];
  const int tid = threadIdx.x, lane = tid & 63, w = tid >> 6;
  const int wr = w >> 1, wc = w & 1, cl = lane & 15, hi = lane >> 4;
  const int m0 = blockIdx.x * 128, n0 = blockIdx.y * 128;
  const int lr = lane >> 3;
  const int swz = ((lane & 7) ^ lr) * 8;  // pre-swizzled source chunk (XOR by lds row&7)

  const uint16_t* asrc[4];
  const uint16_t* bsrc[4];
  uint16_t* adst[4];
  uint16_t* bdst[4];
#pragma unroll
  for (int c = 0; c < 4; ++c) {
    const int seg = c * 4 + w;
    asrc[c] = A + (size_t)(m0 + seg * 8 + lr) * 1024 + swz;
    bsrc[c] = W + (size_t)(n0 + seg * 8 + lr) * 1024 + swz;
    adst[c] = As + seg * 512;
    bdst[c] = Bs + seg * 512;
  }
  int aoff[4][2], boff[4][2];
#pragma unroll
  for (int m = 0; m < 4; ++m)
#pragma unroll
    for (int kk = 0; kk < 2; ++kk) {
      const int ra = wr * 64 + m * 16 + cl, rb = wc * 64 + m * 16 + cl;
      aoff[m][kk] = ra * 64 + (((kk * 4 + hi) ^ (ra & 7)) * 8);
      boff[m][kk] = rb * 64 + (((kk * 4 + hi) ^ (rb & 7)) * 8);
    }

  f32x4 acc[4][4];
#pragma unroll
  for (int m = 0; m < 4; ++m)
#pragma unroll
    for (int n = 0; n < 4; ++n) acc[m][n] = (f32x4){0.f, 0.f, 0.f, 0.f};

  for (int kt = 0; kt < 16; ++kt) {
    const int k0 = kt * 64;
#pragma unroll
    for (int c = 0; c < 4; ++c) {
      gload16(asrc[c] + k0, adst[c]);
      gload16(bsrc[c] + k0, bdst[c]);
    }
    asm volatile("s_waitcnt vmcnt(0)" ::: "memory");
    __syncthreads();
#pragma unroll
    for (int kk = 0; kk < 2; ++kk) {
      bf16x8 af[4], bfr[4];
#pragma unroll
      for (int m = 0; m < 4; ++m) af[m] = *(const bf16x8*)(As + aoff[m][kk]);
#pragma unroll
      for (int n = 0; n < 4; ++n) bfr[n] = *(const bf16x8*)(Bs + boff[n][kk]);
#pragma unroll
      for (int m = 0; m < 4; ++m)
#pragma unroll
        for (int n = 0; n < 4; ++n) acc[m][n] = mfma16(af[m], bfr[n], acc[m][n]);
    }
    __syncthreads();
  }

#pragma unroll
  for (int n = 0; n < 4; ++n) {
    const int col = n0 + wc * 64 + n * 16 + cl;
    const float bv = bias[col];
    const int h = col >> 6, dk = col & 63;
#pragma unroll
    for (int m = 0; m < 4; ++m) {
      const int row0 = m0 + wr * 64 + m * 16 + hi * 4;
#pragma unroll
      for (int j = 0; j < 4; ++j) {
        const int row = row0 + j;
        const float val = acc[m][n][j] + bv;
        const int b = row >> 11, s = row & 2047;
        if constexpr (MODE == 0) {
          out16[((size_t)(b * 16 + h) * 2048 + s) * 64 + dk] = f2bf(val * QSCALE);
        } else if constexpr (MODE == 1) {
          out16[((size_t)(b * 16 + h) * 2048 + s) * 64 + dk] = f2bf(val);
        } else if constexpr (MODE == 2) {
          out16[((size_t)(b * 16 + h) * 64 + dk) * 2048 + s] = f2bf(val);
        } else {
          out32[(size_t)row * 1024 + col] = val;
        }
      }
    }
  }
}

// ---------------- flash attention, swapped-QK^T, in-register softmax ----------------
// q_ws (log2-prescaled), k_ws: [BH, S, 64]; vt_ws: [BH, 64, S]; o_ws: [B, S, 1024] bf16.
__global__ __launch_bounds__(512) void attn_k(const uint16_t* __restrict__ q_ws,
                                              const uint16_t* __restrict__ k_ws,
                                              const uint16_t* __restrict__ vt_ws,
                                              uint16_t* __restrict__ o_ws) {
  __shared__ __align__(16) uint16_t Ks[2][4096];  // [kv 64][dk 64] swizzled image
  __shared__ __align__(16) uint16_t Vs[2][4096];  // [dk 64][kv 64] swizzled image
  __shared__ __align__(16) uint16_t Ps[8][1152];  // per-wave [q 16][kv 64 pad 72]

  const int tid = threadIdx.x, lane = tid & 63, w = tid >> 6;
  const int cl = lane & 15, hi = lane >> 4;
  const int bh = blockIdx.y, b = bh >> 4, h = bh & 15;
  const int q0 = blockIdx.x * 128;
  const int lr = lane >> 3;
  const int swz = ((lane & 7) ^ lr) * 8;

  // Q fragments (B-operand; q = w*16+cl is this lane's own row)
  bf16x8 qf[2];
  {
    const uint16_t* qp = q_ws + ((size_t)bh * 2048 + q0 + w * 16 + cl) * 64 + hi * 8;
    qf[0] = *(const bf16x8*)(qp);
    qf[1] = *(const bf16x8*)(qp + 32);
  }

  const uint16_t* ksrc = k_ws + (size_t)bh * 131072 + (size_t)(w * 8 + lr) * 64 + swz;
  const uint16_t* vsrc = vt_ws + (size_t)bh * 131072 + (size_t)(w * 8 + lr) * 2048 + swz;

  float m_run = -1e30f, lsum = 0.f;
  f32x4 oT[4];
#pragma unroll
  for (int f = 0; f < 4; ++f) oT[f] = (f32x4){0.f, 0.f, 0.f, 0.f};

  uint16_t* pw = Ps[w];
  const int pwr = cl * 72;

  // prologue: stage tile 0
  gload16(ksrc, &Ks[0][w * 512]);
  gload16(vsrc, &Vs[0][w * 512]);
  asm volatile("s_waitcnt vmcnt(0)" ::: "memory");
  __syncthreads();

  int cur = 0;
  for (int kt = 0; kt < 32; ++kt) {
    if (kt < 31) {  // prefetch next tile into the other buffer (overlaps compute)
      gload16(ksrc + (size_t)(kt + 1) * 4096, &Ks[cur ^ 1][w * 512]);
      gload16(vsrc + (kt + 1) * 64, &Vs[cur ^ 1][w * 512]);
    }

    // S^T = mfma(K, Q): sa[f][j] = S[q=w*16+cl][kv = f*16+hi*4+j] (log2 domain)
    f32x4 sa[4];
#pragma unroll
    for (int f = 0; f < 4; ++f) sa[f] = (f32x4){0.f, 0.f, 0.f, 0.f};
    const uint16_t* kb = Ks[cur];
#pragma unroll
    for (int kk = 0; kk < 2; ++kk) {
#pragma unroll
      for (int f = 0; f < 4; ++f) {
        bf16x8 kf = *(const bf16x8*)(kb + (f * 16 + cl) * 64 + (((kk * 4 + hi) ^ (cl & 7)) * 8));
        sa[f] = mfma16(kf, qf[kk], sa[f]);
      }
    }

    // online softmax: lane owns one q-row; 16 in-lane values + hi-group shfls
    f32x4 t = max4(max4(sa[0], sa[1]), max4(sa[2], sa[3]));
    float mx = fmaxf(fmaxf(t[0], t[1]), fmaxf(t[2], t[3]));
    mx = fmaxf(mx, __shfl_xor(mx, 16));
    mx = fmaxf(mx, __shfl_xor(mx, 32));
    const float mn = fmaxf(m_run, mx);
    const float al = __builtin_amdgcn_exp2f(m_run - mn);
    m_run = mn;
    float ps = 0.f;
#pragma unroll
    for (int f = 0; f < 4; ++f)
#pragma unroll
      for (int j = 0; j < 4; ++j) {
        const float p = __builtin_amdgcn_exp2f(sa[f][j] - mn);
        sa[f][j] = p;
        ps += p;
      }
    ps += __shfl_xor(ps, 16);
    ps += __shfl_xor(ps, 32);
    lsum = lsum * al + ps;
#pragma unroll
    for (int f = 0; f < 4; ++f) oT[f] = oT[f] * al;

    // P -> per-wave LDS, packed b64 writes
#pragma unroll
    for (int f = 0; f < 4; ++f) {
      u32x2 pv;
      pv[0] = (uint32_t)f2bf(sa[f][0]) | ((uint32_t)f2bf(sa[f][1]) << 16);
      pv[1] = (uint32_t)f2bf(sa[f][2]) | ((uint32_t)f2bf(sa[f][3]) << 16);
      *(u32x2*)(pw + pwr + f * 16 + hi * 4) = pv;
    }
    asm volatile("s_waitcnt lgkmcnt(0)" ::: "memory");
    __builtin_amdgcn_sched_barrier(0);

    // O^T += mfma(V^T, P^T)
    const uint16_t* vb = Vs[cur];
#pragma unroll
    for (int ks = 0; ks < 2; ++ks) {
      bf16x8 pf = *(const bf16x8*)(pw + pwr + ks * 32 + hi * 8);
#pragma unroll
      for (int ft = 0; ft < 4; ++ft) {
        bf16x8 vf = *(const bf16x8*)(vb + (ft * 16 + cl) * 64 + (((ks * 4 + hi) ^ (cl & 7)) * 8));
        oT[ft] = mfma16(vf, pf, oT[ft]);
      }
    }

    asm volatile("s_waitcnt vmcnt(0)" ::: "memory");  // next tile staged
    __syncthreads();                                   // + everyone done reading cur
    cur ^= 1;
  }

  // epilogue: normalize, transpose via Ps, coalesced store
  const float inv = 1.0f / lsum;
#pragma unroll
  for (int ft = 0; ft < 4; ++ft) {
    u32x2 pv;
    pv[0] = (uint32_t)f2bf(oT[ft][0] * inv) | ((uint32_t)f2bf(oT[ft][1] * inv) << 16);
    pv[1] = (uint32_t)f2bf(oT[ft][2] * inv) | ((uint32_t)f2bf(oT[ft][3] * inv) << 16);
    *(u32x2*)(pw + pwr + ft * 16 + hi * 4) = pv;
  }
  asm volatile("s_waitcnt lgkmcnt(0)" ::: "memory");
  __builtin_amdgcn_sched_barrier(0);
  {
    const int r = lane >> 2, c4 = lane & 3;
    const uint16_t* rp = pw + r * 72 + c4 * 16;
    bf16x8 o0 = *(const bf16x8*)(rp);
    bf16x8 o1 = *(const bf16x8*)(rp + 8);
    uint16_t* op = o_ws + ((size_t)b * 2048 + q0 + w * 16 + r) * 1024 + h * 64 + c4 * 16;
    *(bf16x8*)(op) = o0;
    *(bf16x8*)(op + 8) = o1;
  }
}

// ---------------- launch ----------------
extern "C" void kernel_launch(void* const* d_in, const int* in_sizes, int n_in,
                              void* d_out, int out_size, void* d_ws, size_t ws_size,
                              hipStream_t stream) {
  const float* Q  = (const float*)d_in[0];
  const float* K  = (const float*)d_in[1];
  const float* V  = (const float*)d_in[2];
  const float* Wq = (const float*)d_in[3];
  const float* bq = (const float*)d_in[4];
  const float* Wk = (const float*)d_in[5];
  const float* bk = (const float*)d_in[6];
  const float* Wv = (const float*)d_in[7];
  const float* bv = (const float*)d_in[8];
  const float* Wo = (const float*)d_in[9];
  const float* bo = (const float*)d_in[10];

  uint16_t* ws    = (uint16_t*)d_ws;
  uint16_t* wb    = ws;                  // 4 x 1M bf16 weights
  uint16_t* qb    = ws + 4194304;        // 8M bf16 Q  (reused as o_ws after gemm<0>)
  uint16_t* kb    = qb + 8388608;        // 8M bf16 K
  uint16_t* vb    = kb + 8388608;        // 8M bf16 V
  uint16_t* q_ws  = vb + 8388608;        // [BH,S,64]
  uint16_t* k_ws  = q_ws + 8388608;      // [BH,S,64]
  uint16_t* vt_ws = k_ws + 8388608;      // [BH,64,S]
  uint16_t* o_ws  = qb;                  // alias (qb dead after gemm<0>)
  float* out = (float*)d_out;

  cast_all<<<14336, 256, 0, stream>>>(Q, K, V, Wq, Wk, Wv, Wo, ws);
  gemm_k<0><<<dim3(64, 8), 256, 0, stream>>>(qb, wb + 0 * 1048576, bq, q_ws, nullptr);
  gemm_k<1><<<dim3(64, 8), 256, 0, stream>>>(kb, wb + 1 * 1048576, bk, k_ws, nullptr);
  gemm_k<2><<<dim3(64, 8), 256, 0, stream>>>(vb, wb + 2 * 1048576, bv, vt_ws, nullptr);
  attn_k<<<dim3(16, 64), 512, 0, stream>>>(q_ws, k_ws, vt_ws, o_ws);
  gemm_k<3><<<dim3(64, 8), 256, 0, stream>>>(o_ws, wb + 3 * 1048576, bo, nullptr, out);
}

// Round 6
// 368.524 us; speedup vs baseline: 1.2568x; 1.0281x over previous
//
#include <hip/hip_runtime.h>
#include <stdint.h>

typedef __attribute__((ext_vector_type(8))) short    bf16x8;
typedef __attribute__((ext_vector_type(4))) float    f32x4;
typedef __attribute__((ext_vector_type(8))) uint16_t u16x8;
typedef __attribute__((ext_vector_type(2))) uint32_t u32x2;

static constexpr float QSCALE = 0.18033688011112042f;  // 0.125 * log2(e)

__device__ __forceinline__ uint16_t f2bf(float f) {
  uint32_t u = __builtin_bit_cast(uint32_t, f);
  u += 0x7FFFu + ((u >> 16) & 1u);
  return (uint16_t)(u >> 16);
}
__device__ __forceinline__ f32x4 mfma16(bf16x8 a, bf16x8 b, f32x4 c) {
  return __builtin_amdgcn_mfma_f32_16x16x32_bf16(a, b, c, 0, 0, 0);
}

typedef const __attribute__((address_space(1))) void gas1_t;
typedef __attribute__((address_space(3))) void las3_t;
__device__ __forceinline__ void gload16(const void* g, void* l) {
  __builtin_amdgcn_global_load_lds((gas1_t*)g, (las3_t*)l, 16, 0, 0);
}

__device__ __forceinline__ f32x4 max4(f32x4 a, f32x4 b) {
  f32x4 r;
  r[0] = fmaxf(a[0], b[0]); r[1] = fmaxf(a[1], b[1]);
  r[2] = fmaxf(a[2], b[2]); r[3] = fmaxf(a[3], b[3]);
  return r;
}

// ---------------- cast all fp32 inputs -> bf16 in ws ----------------
__global__ __launch_bounds__(256) void cast_all(const float* __restrict__ Q,
                                                const float* __restrict__ K,
                                                const float* __restrict__ V,
                                                const float* __restrict__ Wq,
                                                const float* __restrict__ Wk,
                                                const float* __restrict__ Wv,
                                                const float* __restrict__ Wo,
                                                uint16_t* __restrict__ ws) {
  const int bx = blockIdx.x;
  const float* src;
  uint16_t* dst;
  int off;
  if (bx < 12288) {
    const int seg = bx >> 12, r = bx & 4095;
    src = (seg == 0) ? Q : (seg == 1) ? K : V;
    dst = ws + 4194304 + (size_t)seg * 8388608;
    off = r * 2048 + threadIdx.x * 8;
  } else {
    const int t = bx - 12288;
    const int seg = t >> 9, r = t & 511;
    src = (seg == 0) ? Wq : (seg == 1) ? Wk : (seg == 2) ? Wv : Wo;
    dst = ws + (size_t)seg * 1048576;
    off = r * 2048 + threadIdx.x * 8;
  }
  f32x4 a = *(const f32x4*)(src + off);
  f32x4 b = *(const f32x4*)(src + off + 4);
  u16x8 o;
  o[0] = f2bf(a[0]); o[1] = f2bf(a[1]); o[2] = f2bf(a[2]); o[3] = f2bf(a[3]);
  o[4] = f2bf(b[0]); o[5] = f2bf(b[1]); o[6] = f2bf(b[2]); o[7] = f2bf(b[3]);
  *(u16x8*)(dst + off) = o;
}

// ---------------- bf16 GEMM: C = A @ W^T + bias (R2 single-buffer + XCD remap) ----------------
template <int MODE>
__global__ __launch_bounds__(256) void gemm_k(const uint16_t* __restrict__ A,
                                              const uint16_t* __restrict__ W,
                                              const float* __restrict__ bias,
                                              uint16_t* __restrict__ out16,
                                              float* __restrict__ out32) {
  __shared__ __align__(16) uint16_t As[128 * 64];
  __shared__ __align__(16) uint16_t Bs[128 * 64];
  const int tid = threadIdx.x, lane = tid & 63, w = tid >> 6;
  const int wr = w >> 1, wc = w & 1, cl = lane & 15, hi = lane >> 4;
  // XCD remap (bijective): each XCD owns an 8x8 block of (m,n) tiles
  const int bid = blockIdx.x;
  const int xcd = bid & 7, idx = bid >> 3;
  const int m0 = (xcd * 8 + (idx >> 3)) * 128;
  const int n0 = (idx & 7) * 128;
  const int lr = lane >> 3;
  const int swz = ((lane & 7) ^ lr) * 8;  // pre-swizzled source chunk (XOR by lds row&7)

  const uint16_t* asrc[4];
  const uint16_t* bsrc[4];
  uint16_t* adst[4];
  uint16_t* bdst[4];
#pragma unroll
  for (int c = 0; c < 4; ++c) {
    const int seg = c * 4 + w;
    asrc[c] = A + (size_t)(m0 + seg * 8 + lr) * 1024 + swz;
    bsrc[c] = W + (size_t)(n0 + seg * 8 + lr) * 1024 + swz;
    adst[c] = As + seg * 512;
    bdst[c] = Bs + seg * 512;
  }
  int aoff[4][2], boff[4][2];
#pragma unroll
  for (int m = 0; m < 4; ++m)
#pragma unroll
    for (int kk = 0; kk < 2; ++kk) {
      const int ra = wr * 64 + m * 16 + cl, rb = wc * 64 + m * 16 + cl;
      aoff[m][kk] = ra * 64 + (((kk * 4 + hi) ^ (ra & 7)) * 8);
      boff[m][kk] = rb * 64 + (((kk * 4 + hi) ^ (rb & 7)) * 8);
    }

  f32x4 acc[4][4];
#pragma unroll
  for (int m = 0; m < 4; ++m)
#pragma unroll
    for (int n = 0; n < 4; ++n) acc[m][n] = (f32x4){0.f, 0.f, 0.f, 0.f};

  for (int kt = 0; kt < 16; ++kt) {
    const int k0 = kt * 64;
#pragma unroll
    for (int c = 0; c < 4; ++c) {
      gload16(asrc[c] + k0, adst[c]);
      gload16(bsrc[c] + k0, bdst[c]);
    }
    asm volatile("s_waitcnt vmcnt(0)" ::: "memory");
    __syncthreads();
#pragma unroll
    for (int kk = 0; kk < 2; ++kk) {
      bf16x8 af[4], bfr[4];
#pragma unroll
      for (int m = 0; m < 4; ++m) af[m] = *(const bf16x8*)(As + aoff[m][kk]);
#pragma unroll
      for (int n = 0; n < 4; ++n) bfr[n] = *(const bf16x8*)(Bs + boff[n][kk]);
#pragma unroll
      for (int m = 0; m < 4; ++m)
#pragma unroll
        for (int n = 0; n < 4; ++n) acc[m][n] = mfma16(af[m], bfr[n], acc[m][n]);
    }
    __syncthreads();
  }

#pragma unroll
  for (int n = 0; n < 4; ++n) {
    const int col = n0 + wc * 64 + n * 16 + cl;
    const float bv = bias[col];
    const int h = col >> 6, dk = col & 63;
#pragma unroll
    for (int m = 0; m < 4; ++m) {
      const int row0 = m0 + wr * 64 + m * 16 + hi * 4;
#pragma unroll
      for (int j = 0; j < 4; ++j) {
        const int row = row0 + j;
        const float val = acc[m][n][j] + bv;
        const int b = row >> 11, s = row & 2047;
        if constexpr (MODE == 0) {
          out16[((size_t)(b * 16 + h) * 2048 + s) * 64 + dk] = f2bf(val * QSCALE);
        } else if constexpr (MODE == 1) {
          out16[((size_t)(b * 16 + h) * 2048 + s) * 64 + dk] = f2bf(val);
        } else if constexpr (MODE == 2) {
          out16[((size_t)(b * 16 + h) * 64 + dk) * 2048 + s] = f2bf(val);
        } else {
          out32[(size_t)row * 1024 + col] = val;
        }
      }
    }
  }
}

// ---------------- flash attention (R2 structure + XCD remap) ----------------
__global__ __launch_bounds__(512) void attn_k(const uint16_t* __restrict__ q_ws,
                                              const uint16_t* __restrict__ k_ws,
                                              const uint16_t* __restrict__ vt_ws,
                                              uint16_t* __restrict__ o_ws) {
  __shared__ __align__(16) uint16_t Ks[2][4096];
  __shared__ __align__(16) uint16_t Vs[2][4096];
  __shared__ __align__(16) uint16_t Ps[8][1152];  // per-wave [q 16][kv 64 pad 72]

  const int tid = threadIdx.x, lane = tid & 63, w = tid >> 6;
  const int cl = lane & 15, hi = lane >> 4;
  // XCD remap (bijective): all 16 q-tiles of one (b,h) on the same XCD
  const int id = blockIdx.x;
  const int xcd = id & 7, idx = id >> 3;
  const int bh = xcd * 8 + (idx >> 4);
  const int q0 = (idx & 15) * 128;
  const int b = bh >> 4, h = bh & 15;
  const int lr = lane >> 3;
  const int swz = ((lane & 7) ^ lr) * 8;

  bf16x8 qf[2];
  {
    const uint16_t* qp = q_ws + ((size_t)bh * 2048 + q0 + w * 16 + cl) * 64 + hi * 8;
    qf[0] = *(const bf16x8*)(qp);
    qf[1] = *(const bf16x8*)(qp + 32);
  }

  const uint16_t* ksrc = k_ws + (size_t)bh * 131072 + (size_t)(w * 8 + lr) * 64 + swz;
  const uint16_t* vsrc = vt_ws + (size_t)bh * 131072 + (size_t)(w * 8 + lr) * 2048 + swz;

  float m_run = -1e30f, lsum = 0.f;
  f32x4 oT[4];
#pragma unroll
  for (int f = 0; f < 4; ++f) oT[f] = (f32x4){0.f, 0.f, 0.f, 0.f};

  uint16_t* pw = Ps[w];
  const int pwr = cl * 72;

  gload16(ksrc, &Ks[0][w * 512]);
  gload16(vsrc, &Vs[0][w * 512]);
  asm volatile("s_waitcnt vmcnt(0)" ::: "memory");
  __syncthreads();

  int cur = 0;
  for (int kt = 0; kt < 32; ++kt) {
    if (kt < 31) {
      gload16(ksrc + (size_t)(kt + 1) * 4096, &Ks[cur ^ 1][w * 512]);
      gload16(vsrc + (kt + 1) * 64, &Vs[cur ^ 1][w * 512]);
    }

    // S^T = mfma(K, Q): sa[f][j] = S[q=w*16+cl][kv=f*16+hi*4+j] (log2 domain)
    f32x4 sa[4];
#pragma unroll
    for (int f = 0; f < 4; ++f) sa[f] = (f32x4){0.f, 0.f, 0.f, 0.f};
    const uint16_t* kb = Ks[cur];
#pragma unroll
    for (int kk = 0; kk < 2; ++kk) {
#pragma unroll
      for (int f = 0; f < 4; ++f) {
        bf16x8 kf = *(const bf16x8*)(kb + (f * 16 + cl) * 64 + (((kk * 4 + hi) ^ (cl & 7)) * 8));
        sa[f] = mfma16(kf, qf[kk], sa[f]);
      }
    }

    // online softmax: lane owns one q-row
    f32x4 t = max4(max4(sa[0], sa[1]), max4(sa[2], sa[3]));
    float mx = fmaxf(fmaxf(t[0], t[1]), fmaxf(t[2], t[3]));
    mx = fmaxf(mx, __shfl_xor(mx, 16));
    mx = fmaxf(mx, __shfl_xor(mx, 32));
    const float mn = fmaxf(m_run, mx);
    const float al = __builtin_amdgcn_exp2f(m_run - mn);
    m_run = mn;
    float ps = 0.f;
#pragma unroll
    for (int f = 0; f < 4; ++f)
#pragma unroll
      for (int j = 0; j < 4; ++j) {
        const float p = __builtin_amdgcn_exp2f(sa[f][j] - mn);
        sa[f][j] = p;
        ps += p;
      }
    ps += __shfl_xor(ps, 16);
    ps += __shfl_xor(ps, 32);
    lsum = lsum * al + ps;
#pragma unroll
    for (int f = 0; f < 4; ++f) oT[f] = oT[f] * al;

    // P -> per-wave LDS, packed b64 writes
#pragma unroll
    for (int f = 0; f < 4; ++f) {
      u32x2 pv;
      pv[0] = (uint32_t)f2bf(sa[f][0]) | ((uint32_t)f2bf(sa[f][1]) << 16);
      pv[1] = (uint32_t)f2bf(sa[f][2]) | ((uint32_t)f2bf(sa[f][3]) << 16);
      *(u32x2*)(pw + pwr + f * 16 + hi * 4) = pv;
    }
    asm volatile("s_waitcnt lgkmcnt(0)" ::: "memory");
    __builtin_amdgcn_sched_barrier(0);

    // O^T += mfma(V^T, P^T)
    const uint16_t* vb = Vs[cur];
#pragma unroll
    for (int ks = 0; ks < 2; ++ks) {
      bf16x8 pf = *(const bf16x8*)(pw + pwr + ks * 32 + hi * 8);
#pragma unroll
      for (int ft = 0; ft < 4; ++ft) {
        bf16x8 vf = *(const bf16x8*)(vb + (ft * 16 + cl) * 64 + (((ks * 4 + hi) ^ (cl & 7)) * 8));
        oT[ft] = mfma16(vf, pf, oT[ft]);
      }
    }

    asm volatile("s_waitcnt vmcnt(0)" ::: "memory");
    __syncthreads();
    cur ^= 1;
  }

  // epilogue: normalize, transpose via Ps, coalesced store
  const float inv = 1.0f / lsum;
#pragma unroll
  for (int ft = 0; ft < 4; ++ft) {
    u32x2 pv;
    pv[0] = (uint32_t)f2bf(oT[ft][0] * inv) | ((uint32_t)f2bf(oT[ft][1] * inv) << 16);
    pv[1] = (uint32_t)f2bf(oT[ft][2] * inv) | ((uint32_t)f2bf(oT[ft][3] * inv) << 16);
    *(u32x2*)(pw + pwr + ft * 16 + hi * 4) = pv;
  }
  asm volatile("s_waitcnt lgkmcnt(0)" ::: "memory");
  __builtin_amdgcn_sched_barrier(0);
  {
    const int r = lane >> 2, c4 = lane & 3;
    const uint16_t* rp = pw + r * 72 + c4 * 16;
    bf16x8 o0 = *(const bf16x8*)(rp);
    bf16x8 o1 = *(const bf16x8*)(rp + 8);
    uint16_t* op = o_ws + ((size_t)b * 2048 + q0 + w * 16 + r) * 1024 + h * 64 + c4 * 16;
    *(bf16x8*)(op) = o0;
    *(bf16x8*)(op + 8) = o1;
  }
}

// ---------------- launch ----------------
extern "C" void kernel_launch(void* const* d_in, const int* in_sizes, int n_in,
                              void* d_out, int out_size, void* d_ws, size_t ws_size,
                              hipStream_t stream) {
  const float* Q  = (const float*)d_in[0];
  const float* K  = (const float*)d_in[1];
  const float* V  = (const float*)d_in[2];
  const float* Wq = (const float*)d_in[3];
  const float* bq = (const float*)d_in[4];
  const float* Wk = (const float*)d_in[5];
  const float* bk = (const float*)d_in[6];
  const float* Wv = (const float*)d_in[7];
  const float* bv = (const float*)d_in[8];
  const float* Wo = (const float*)d_in[9];
  const float* bo = (const float*)d_in[10];

  uint16_t* ws    = (uint16_t*)d_ws;
  uint16_t* wb    = ws;                  // 4 x 1M bf16 weights
  uint16_t* qb    = ws + 4194304;        // 8M bf16 Q (reused as o_ws after gemm<0>)
  uint16_t* kb    = qb + 8388608;
  uint16_t* vb    = kb + 8388608;
  uint16_t* q_ws  = vb + 8388608;        // [BH,S,64]
  uint16_t* k_ws  = q_ws + 8388608;      // [BH,S,64]
  uint16_t* vt_ws = k_ws + 8388608;      // [BH,64,S]
  uint16_t* o_ws  = qb;                  // alias
  float* out = (float*)d_out;

  cast_all<<<14336, 256, 0, stream>>>(Q, K, V, Wq, Wk, Wv, Wo, ws);
  gemm_k<0><<<512, 256, 0, stream>>>(qb, wb + 0 * 1048576, bq, q_ws, nullptr);
  gemm_k<1><<<512, 256, 0, stream>>>(kb, wb + 1 * 1048576, bk, k_ws, nullptr);
  gemm_k<2><<<512, 256, 0, stream>>>(vb, wb + 2 * 1048576, bv, vt_ws, nullptr);
  attn_k<<<1024, 512, 0, stream>>>(q_ws, k_ws, vt_ws, o_ws);
  gemm_k<3><<<512, 256, 0, stream>>>(o_ws, wb + 3 * 1048576, bo, nullptr, out);
}

// Round 8
// 358.630 us; speedup vs baseline: 1.2915x; 1.0276x over previous
//
#include <hip/hip_runtime.h>
#include <stdint.h>

typedef __attribute__((ext_vector_type(8))) short    bf16x8;
typedef __attribute__((ext_vector_type(4))) float    f32x4;
typedef __attribute__((ext_vector_type(8))) uint16_t u16x8;
typedef __attribute__((ext_vector_type(2))) uint32_t u32x2;

static constexpr float QSCALE = 0.18033688011112042f;  // 0.125 * log2(e)

__device__ __forceinline__ uint16_t f2bf(float f) {
  uint32_t u = __builtin_bit_cast(uint32_t, f);
  u += 0x7FFFu + ((u >> 16) & 1u);
  return (uint16_t)(u >> 16);
}
__device__ __forceinline__ uint32_t cvtpk(float lo, float hi) {
  uint32_t r;
  asm("v_cvt_pk_bf16_f32 %0, %1, %2" : "=v"(r) : "v"(lo), "v"(hi));
  return r;
}
__device__ __forceinline__ f32x4 mfma16(bf16x8 a, bf16x8 b, f32x4 c) {
  return __builtin_amdgcn_mfma_f32_16x16x32_bf16(a, b, c, 0, 0, 0);
}

typedef const __attribute__((address_space(1))) void gas1_t;
typedef __attribute__((address_space(3))) void las3_t;
__device__ __forceinline__ void gload16(const void* g, void* l) {
  __builtin_amdgcn_global_load_lds((gas1_t*)g, (las3_t*)l, 16, 0, 0);
}

__device__ __forceinline__ f32x4 max4(f32x4 a, f32x4 b) {
  f32x4 r;
  r[0] = fmaxf(a[0], b[0]); r[1] = fmaxf(a[1], b[1]);
  r[2] = fmaxf(a[2], b[2]); r[3] = fmaxf(a[3], b[3]);
  return r;
}

// ---------------- cast all fp32 inputs -> bf16 in ws ----------------
__global__ __launch_bounds__(256) void cast_all(const float* __restrict__ Q,
                                                const float* __restrict__ K,
                                                const float* __restrict__ V,
                                                const float* __restrict__ Wq,
                                                const float* __restrict__ Wk,
                                                const float* __restrict__ Wv,
                                                const float* __restrict__ Wo,
                                                uint16_t* __restrict__ ws) {
  const int bx = blockIdx.x;
  const float* src;
  uint16_t* dst;
  int off;
  if (bx < 12288) {
    const int seg = bx >> 12, r = bx & 4095;
    src = (seg == 0) ? Q : (seg == 1) ? K : V;
    dst = ws + 4194304 + (size_t)seg * 8388608;
    off = r * 2048 + threadIdx.x * 8;
  } else {
    const int t = bx - 12288;
    const int seg = t >> 9, r = t & 511;
    src = (seg == 0) ? Wq : (seg == 1) ? Wk : (seg == 2) ? Wv : Wo;
    dst = ws + (size_t)seg * 1048576;
    off = r * 2048 + threadIdx.x * 8;
  }
  f32x4 a = *(const f32x4*)(src + off);
  f32x4 b = *(const f32x4*)(src + off + 4);
  u16x8 o;
  o[0] = f2bf(a[0]); o[1] = f2bf(a[1]); o[2] = f2bf(a[2]); o[3] = f2bf(a[3]);
  o[4] = f2bf(b[0]); o[5] = f2bf(b[1]); o[6] = f2bf(b[2]); o[7] = f2bf(b[3]);
  *(u16x8*)(dst + off) = o;
}

// ---------------- bf16 GEMM: C = A @ W^T + bias (R6-identical) ----------------
template <int MODE>
__global__ __launch_bounds__(256) void gemm_k(const uint16_t* __restrict__ A,
                                              const uint16_t* __restrict__ W,
                                              const float* __restrict__ bias,
                                              uint16_t* __restrict__ out16,
                                              float* __restrict__ out32) {
  __shared__ __align__(16) uint16_t As[128 * 64];
  __shared__ __align__(16) uint16_t Bs[128 * 64];
  const int tid = threadIdx.x, lane = tid & 63, w = tid >> 6;
  const int wr = w >> 1, wc = w & 1, cl = lane & 15, hi = lane >> 4;
  const int bid = blockIdx.x;
  const int xcd = bid & 7, idx = bid >> 3;
  const int m0 = (xcd * 8 + (idx >> 3)) * 128;
  const int n0 = (idx & 7) * 128;
  const int lr = lane >> 3;
  const int swz = ((lane & 7) ^ lr) * 8;

  const uint16_t* asrc[4];
  const uint16_t* bsrc[4];
  uint16_t* adst[4];
  uint16_t* bdst[4];
#pragma unroll
  for (int c = 0; c < 4; ++c) {
    const int seg = c * 4 + w;
    asrc[c] = A + (size_t)(m0 + seg * 8 + lr) * 1024 + swz;
    bsrc[c] = W + (size_t)(n0 + seg * 8 + lr) * 1024 + swz;
    adst[c] = As + seg * 512;
    bdst[c] = Bs + seg * 512;
  }
  int aoff[4][2], boff[4][2];
#pragma unroll
  for (int m = 0; m < 4; ++m)
#pragma unroll
    for (int kk = 0; kk < 2; ++kk) {
      const int ra = wr * 64 + m * 16 + cl, rb = wc * 64 + m * 16 + cl;
      aoff[m][kk] = ra * 64 + (((kk * 4 + hi) ^ (ra & 7)) * 8);
      boff[m][kk] = rb * 64 + (((kk * 4 + hi) ^ (rb & 7)) * 8);
    }

  f32x4 acc[4][4];
#pragma unroll
  for (int m = 0; m < 4; ++m)
#pragma unroll
    for (int n = 0; n < 4; ++n) acc[m][n] = (f32x4){0.f, 0.f, 0.f, 0.f};

  for (int kt = 0; kt < 16; ++kt) {
    const int k0 = kt * 64;
#pragma unroll
    for (int c = 0; c < 4; ++c) {
      gload16(asrc[c] + k0, adst[c]);
      gload16(bsrc[c] + k0, bdst[c]);
    }
    asm volatile("s_waitcnt vmcnt(0)" ::: "memory");
    __syncthreads();
#pragma unroll
    for (int kk = 0; kk < 2; ++kk) {
      bf16x8 af[4], bfr[4];
#pragma unroll
      for (int m = 0; m < 4; ++m) af[m] = *(const bf16x8*)(As + aoff[m][kk]);
#pragma unroll
      for (int n = 0; n < 4; ++n) bfr[n] = *(const bf16x8*)(Bs + boff[n][kk]);
#pragma unroll
      for (int m = 0; m < 4; ++m)
#pragma unroll
        for (int n = 0; n < 4; ++n) acc[m][n] = mfma16(af[m], bfr[n], acc[m][n]);
    }
    __syncthreads();
  }

#pragma unroll
  for (int n = 0; n < 4; ++n) {
    const int col = n0 + wc * 64 + n * 16 + cl;
    const float bv = bias[col];
    const int h = col >> 6, dk = col & 63;
#pragma unroll
    for (int m = 0; m < 4; ++m) {
      const int row0 = m0 + wr * 64 + m * 16 + hi * 4;
#pragma unroll
      for (int j = 0; j < 4; ++j) {
        const int row = row0 + j;
        const float val = acc[m][n][j] + bv;
        const int b = row >> 11, s = row & 2047;
        if constexpr (MODE == 0) {
          out16[((size_t)(b * 16 + h) * 2048 + s) * 64 + dk] = f2bf(val * QSCALE);
        } else if constexpr (MODE == 1) {
          out16[((size_t)(b * 16 + h) * 2048 + s) * 64 + dk] = f2bf(val);
        } else if constexpr (MODE == 2) {
          out16[((size_t)(b * 16 + h) * 64 + dk) * 2048 + s] = f2bf(val);
        } else {
          out32[(size_t)row * 1024 + col] = val;
        }
      }
    }
  }
}

// ---------------- flash attention (R6 base + defer-max + cvt_pk; scalar shfl lsum) ----------------
__global__ __launch_bounds__(512) void attn_k(const uint16_t* __restrict__ q_ws,
                                              const uint16_t* __restrict__ k_ws,
                                              const uint16_t* __restrict__ vt_ws,
                                              uint16_t* __restrict__ o_ws) {
  __shared__ __align__(16) uint16_t Ks[2][4096];
  __shared__ __align__(16) uint16_t Vs[2][4096];
  __shared__ __align__(16) uint16_t Ps[8][1152];  // per-wave [q 16][kv 64 pad 72]

  const int tid = threadIdx.x, lane = tid & 63, w = tid >> 6;
  const int cl = lane & 15, hi = lane >> 4;
  const int id = blockIdx.x;
  const int xcd = id & 7, idx = id >> 3;
  const int bh = xcd * 8 + (idx >> 4);
  const int q0 = (idx & 15) * 128;
  const int b = bh >> 4, h = bh & 15;
  const int lr = lane >> 3;
  const int swz = ((lane & 7) ^ lr) * 8;

  bf16x8 qf[2];
  {
    const uint16_t* qp = q_ws + ((size_t)bh * 2048 + q0 + w * 16 + cl) * 64 + hi * 8;
    qf[0] = *(const bf16x8*)(qp);
    qf[1] = *(const bf16x8*)(qp + 32);
  }

  const uint16_t* ksrc = k_ws + (size_t)bh * 131072 + (size_t)(w * 8 + lr) * 64 + swz;
  const uint16_t* vsrc = vt_ws + (size_t)bh * 131072 + (size_t)(w * 8 + lr) * 2048 + swz;

  float m_run = -1e30f, lsum = 0.f;
  f32x4 oT[4];
#pragma unroll
  for (int f = 0; f < 4; ++f) oT[f] = (f32x4){0.f, 0.f, 0.f, 0.f};

  uint16_t* pw = Ps[w];
  const int pwr = cl * 72;

  gload16(ksrc, &Ks[0][w * 512]);
  gload16(vsrc, &Vs[0][w * 512]);
  asm volatile("s_waitcnt vmcnt(0)" ::: "memory");
  __syncthreads();

  int cur = 0;
  for (int kt = 0; kt < 32; ++kt) {
    if (kt < 31) {
      gload16(ksrc + (size_t)(kt + 1) * 4096, &Ks[cur ^ 1][w * 512]);
      gload16(vsrc + (kt + 1) * 64, &Vs[cur ^ 1][w * 512]);
    }

    // S^T = mfma(K, Q): sa[f][j] = S[q=w*16+cl][kv=f*16+hi*4+j] (log2 domain)
    f32x4 sa[4];
#pragma unroll
    for (int f = 0; f < 4; ++f) sa[f] = (f32x4){0.f, 0.f, 0.f, 0.f};
    const uint16_t* kb = Ks[cur];
#pragma unroll
    for (int kk = 0; kk < 2; ++kk) {
#pragma unroll
      for (int f = 0; f < 4; ++f) {
        bf16x8 kf = *(const bf16x8*)(kb + (f * 16 + cl) * 64 + (((kk * 4 + hi) ^ (cl & 7)) * 8));
        sa[f] = mfma16(kf, qf[kk], sa[f]);
      }
    }

    // row max for this lane's q-row (lanes {cl, cl+16, cl+32, cl+48} share a row)
    f32x4 t = max4(max4(sa[0], sa[1]), max4(sa[2], sa[3]));
    float mx = fmaxf(fmaxf(t[0], t[1]), fmaxf(t[2], t[3]));
    mx = fmaxf(mx, __shfl_xor(mx, 16));
    mx = fmaxf(mx, __shfl_xor(mx, 32));
    // defer-max (log2 units): rescale only when max grew past threshold
    if (__any(mx > m_run + 8.f)) {
      const float mn = fmaxf(m_run, mx);
      const float al = __builtin_amdgcn_exp2f(m_run - mn);
      m_run = mn;
#pragma unroll
      for (int f = 0; f < 4; ++f) oT[f] = oT[f] * al;
      lsum *= al;
    }

    // P = exp2(sa - m_run) (bounded by 2^8); scalar partial sum + cvt_pk pack
    float ps = 0.f;
#pragma unroll
    for (int f = 0; f < 4; ++f) {
      float p0 = __builtin_amdgcn_exp2f(sa[f][0] - m_run);
      float p1 = __builtin_amdgcn_exp2f(sa[f][1] - m_run);
      float p2 = __builtin_amdgcn_exp2f(sa[f][2] - m_run);
      float p3 = __builtin_amdgcn_exp2f(sa[f][3] - m_run);
      ps += (p0 + p1) + (p2 + p3);
      u32x2 pv;
      pv[0] = cvtpk(p0, p1);
      pv[1] = cvtpk(p2, p3);
      *(u32x2*)(pw + pwr + f * 16 + hi * 4) = pv;
    }
    ps += __shfl_xor(ps, 16);
    ps += __shfl_xor(ps, 32);
    lsum += ps;
    asm volatile("s_waitcnt lgkmcnt(0)" ::: "memory");
    __builtin_amdgcn_sched_barrier(0);

    // O^T += mfma(V^T, P^T)
    const uint16_t* vb = Vs[cur];
#pragma unroll
    for (int ks = 0; ks < 2; ++ks) {
      bf16x8 pf = *(const bf16x8*)(pw + pwr + ks * 32 + hi * 8);
#pragma unroll
      for (int ft = 0; ft < 4; ++ft) {
        bf16x8 vf = *(const bf16x8*)(vb + (ft * 16 + cl) * 64 + (((ks * 4 + hi) ^ (cl & 7)) * 8));
        oT[ft] = mfma16(vf, pf, oT[ft]);
      }
    }

    asm volatile("s_waitcnt vmcnt(0)" ::: "memory");
    __syncthreads();
    cur ^= 1;
  }

  // epilogue: normalize, transpose via Ps, coalesced store
  const float inv = 1.0f / lsum;
#pragma unroll
  for (int ft = 0; ft < 4; ++ft) {
    u32x2 pv;
    pv[0] = cvtpk(oT[ft][0] * inv, oT[ft][1] * inv);
    pv[1] = cvtpk(oT[ft][2] * inv, oT[ft][3] * inv);
    *(u32x2*)(pw + pwr + ft * 16 + hi * 4) = pv;
  }
  asm volatile("s_waitcnt lgkmcnt(0)" ::: "memory");
  __builtin_amdgcn_sched_barrier(0);
  {
    const int r = lane >> 2, c4 = lane & 3;
    const uint16_t* rp = pw + r * 72 + c4 * 16;
    bf16x8 o0 = *(const bf16x8*)(rp);
    bf16x8 o1 = *(const bf16x8*)(rp + 8);
    uint16_t* op = o_ws + ((size_t)b * 2048 + q0 + w * 16 + r) * 1024 + h * 64 + c4 * 16;
    *(bf16x8*)(op) = o0;
    *(bf16x8*)(op + 8) = o1;
  }
}

// ---------------- launch ----------------
extern "C" void kernel_launch(void* const* d_in, const int* in_sizes, int n_in,
                              void* d_out, int out_size, void* d_ws, size_t ws_size,
                              hipStream_t stream) {
  const float* Q  = (const float*)d_in[0];
  const float* K  = (const float*)d_in[1];
  const float* V  = (const float*)d_in[2];
  const float* Wq = (const float*)d_in[3];
  const float* bq = (const float*)d_in[4];
  const float* Wk = (const float*)d_in[5];
  const float* bk = (const float*)d_in[6];
  const float* Wv = (const float*)d_in[7];
  const float* bv = (const float*)d_in[8];
  const float* Wo = (const float*)d_in[9];
  const float* bo = (const float*)d_in[10];

  uint16_t* ws    = (uint16_t*)d_ws;
  uint16_t* wb    = ws;                  // 4 x 1M bf16 weights
  uint16_t* qb    = ws + 4194304;        // 8M bf16 Q (reused as o_ws after gemm<0>)
  uint16_t* kb    = qb + 8388608;
  uint16_t* vb    = kb + 8388608;
  uint16_t* q_ws  = vb + 8388608;        // [BH,S,64]
  uint16_t* k_ws  = q_ws + 8388608;      // [BH,S,64]
  uint16_t* vt_ws = k_ws + 8388608;      // [BH,64,S]
  uint16_t* o_ws  = qb;                  // alias
  float* out = (float*)d_out;

  cast_all<<<14336, 256, 0, stream>>>(Q, K, V, Wq, Wk, Wv, Wo, ws);
  gemm_k<0><<<512, 256, 0, stream>>>(qb, wb + 0 * 1048576, bq, q_ws, nullptr);
  gemm_k<1><<<512, 256, 0, stream>>>(kb, wb + 1 * 1048576, bk, k_ws, nullptr);
  gemm_k<2><<<512, 256, 0, stream>>>(vb, wb + 2 * 1048576, bv, vt_ws, nullptr);
  attn_k<<<1024, 512, 0, stream>>>(q_ws, k_ws, vt_ws, o_ws);
  gemm_k<3><<<512, 256, 0, stream>>>(o_ws, wb + 3 * 1048576, bo, nullptr, out);
}